// Round 1
// baseline (3942.030 us; speedup 1.0000x reference)
//
#include <hip/hip_runtime.h>
#include <stdint.h>

#define DI __device__ __forceinline__

typedef short s16x8 __attribute__((ext_vector_type(8)));
typedef float f32x4 __attribute__((ext_vector_type(4)));

// ---- constants ----
#define NG   2048
#define NP   512
#define TT   100
#define BB   256
#define N4   8192   // 4*NG
#define MR   25600  // B*T

DI unsigned short f32_to_bf16(float f) {
  union { float f; uint32_t u; } x; x.f = f;
  uint32_t r = x.u + 0x7fffu + ((x.u >> 16) & 1u);
  return (unsigned short)(r >> 16);
}

DI void async16(const void* g, void* l) {
  __builtin_amdgcn_global_load_lds((const __attribute__((address_space(1))) void*)g,
                                   (__attribute__((address_space(3))) void*)l,
                                   16, 0, 0);
}

DI f32x4 mfma16(s16x8 a, s16x8 b, f32x4 c) {
  return __builtin_amdgcn_mfma_f32_16x16x32_bf16(a, b, c, 0, 0, 0);
}

// =====================================================================
// Generic bf16 MFMA tile core: BM x 128 tile, BK=32, 256 threads (4 waves
// in 2x2), wave tile (BM/2) x 64. A row-major [M][K] bf16, Bt n-major
// [N][K] bf16. acc: FM x 4 frags (FM = BM/32).
// =====================================================================
template <int BM>
DI void gemm_core(const unsigned short* __restrict__ A, int lda, int m0,
                  const unsigned short* __restrict__ Bt, int ldb, int n0, int K,
                  unsigned short* sA, unsigned short* sB, f32x4* acc) {
  constexpr int FM = BM / 32;
  const int tid  = threadIdx.x;
  const int wave = tid >> 6;
  const int lane = tid & 63;
  const int quad = lane >> 4;
  const int lr   = lane & 15;
  const int wm   = wave >> 1;
  const int wn   = wave & 1;
  const int wb   = wave << 9;  // wave slot in shorts (64 lanes * 8 shorts)

  for (int k0 = 0; k0 < K; k0 += 32) {
    // stage A tile [BM][32]
    {
      const unsigned short* g = A + (size_t)(m0 + (tid >> 2)) * lda + (k0 + ((tid & 3) << 3));
      async16(g, sA + wb);
    }
    if (BM == 128) {
      int c2 = tid + 256;
      const unsigned short* g = A + (size_t)(m0 + (c2 >> 2)) * lda + (k0 + ((c2 & 3) << 3));
      async16(g, sA + 2048 + wb);
    }
    // stage B tile [128][32] (n-major)
    {
      const unsigned short* g = Bt + (size_t)(n0 + (tid >> 2)) * ldb + (k0 + ((tid & 3) << 3));
      async16(g, sB + wb);
      int c2 = tid + 256;
      const unsigned short* g2 = Bt + (size_t)(n0 + (c2 >> 2)) * ldb + (k0 + ((c2 & 3) << 3));
      async16(g2, sB + 2048 + wb);
    }
    __syncthreads();

    s16x8 af[FM], bfr[4];
#pragma unroll
    for (int fm = 0; fm < FM; ++fm) {
      int row = wm * (BM / 2) + fm * 16 + lr;
      af[fm] = *(const s16x8*)(sA + row * 32 + quad * 8);
    }
#pragma unroll
    for (int fn = 0; fn < 4; ++fn) {
      int col = wn * 64 + fn * 16 + lr;
      bfr[fn] = *(const s16x8*)(sB + col * 32 + quad * 8);
    }
#pragma unroll
    for (int fm = 0; fm < FM; ++fm)
#pragma unroll
      for (int fn = 0; fn < 4; ++fn)
        acc[fm * 4 + fn] = mfma16(af[fm], bfr[fn], acc[fm * 4 + fn]);
    __syncthreads();
  }
}

// =====================================================================
// Transpose + fp32->bf16 convert. src fp32 [R][C] row-major ->
// dst bf16 [n(C)][R] row-major. MODE 0: n = c + noff. MODE 1 (lstm_U gate
// interleave): n = (c & 2047)*4 + (c >> 11).
// =====================================================================
template <int MODE>
__global__ __launch_bounds__(256) void k_transpose_bf16(
    const float* __restrict__ src, unsigned short* __restrict__ dst,
    int R, int C, int noff) {
  __shared__ unsigned short tile[64][65];
  int tr0 = blockIdx.x * 64;
  int tc0 = blockIdx.y * 64;
  int tid = threadIdx.x;
#pragma unroll
  for (int i = 0; i < 16; ++i) {
    int idx = tid + i * 256;
    int r = idx >> 6, c = idx & 63;
    tile[r][c] = f32_to_bf16(src[(size_t)(tr0 + r) * C + (tc0 + c)]);
  }
  __syncthreads();
#pragma unroll
  for (int i = 0; i < 16; ++i) {
    int idx = tid + i * 256;
    int cc = idx >> 6, r = idx & 63;
    int c = tc0 + cc;
    int n = (MODE == 0) ? (c + noff) : (((c & 2047) << 2) | (c >> 11));
    dst[(size_t)n * R + (tr0 + r)] = tile[r][cc];
  }
}

__global__ __launch_bounds__(256) void k_cvt(const float* __restrict__ src,
                                             unsigned short* __restrict__ dst, int n) {
  int i = blockIdx.x * 256 + threadIdx.x;
  if (i < n) dst[i] = f32_to_bf16(src[i]);
}

// ---- W2 = M_W @ lstm_W, bias2 = M_b @ lstm_W + lstm_b (gate-reordered) ----
__global__ __launch_bounds__(256) void k_prep_xw_part(
    const float* __restrict__ lstm_W, const float* __restrict__ M_W,
    const float* __restrict__ M_b, float* __restrict__ part) {
  int c = blockIdx.x * 256 + threadIdx.x;   // 0..8191 original column
  int kc = blockIdx.y;
  int k0 = kc * 128;
  float a0 = 0.f, a1 = 0.f, ab = 0.f;
  for (int k = k0; k < k0 + 128; ++k) {
    float w = lstm_W[(size_t)k * N4 + c];
    a0 += M_W[k] * w;
    a1 += M_W[NG + k] * w;
    ab += M_b[k] * w;
  }
  float* p = part + (size_t)kc * 3 * N4;
  p[c] = a0; p[N4 + c] = a1; p[2 * N4 + c] = ab;
}

__global__ __launch_bounds__(256) void k_prep_xw_reduce(
    const float* __restrict__ part, const float* __restrict__ lstm_b,
    float* __restrict__ W2r, float* __restrict__ b2r) {
  int c = blockIdx.x * 256 + threadIdx.x;
  float a0 = 0.f, a1 = 0.f, ab = 0.f;
  for (int kc = 0; kc < 16; ++kc) {
    const float* p = part + (size_t)kc * 3 * N4;
    a0 += p[c]; a1 += p[N4 + c]; ab += p[2 * N4 + c];
  }
  int n = ((c & 2047) << 2) | (c >> 11);   // gate interleave
  W2r[n] = a0; W2r[N4 + n] = a1; b2r[n] = ab + lstm_b[c];
}

// ---- encoders: [h0 | c0] = p0 @ [enc1_W ; enc2_W] packed as N=4096 ----
__global__ __launch_bounds__(256) void k_enc(
    const unsigned short* __restrict__ p0b, const unsigned short* __restrict__ encWt,
    const float* __restrict__ enc1_b, const float* __restrict__ enc2_b,
    unsigned short* __restrict__ hbf, float* __restrict__ cfp) {
  __shared__ __align__(16) unsigned short sA[64 * 32];
  __shared__ __align__(16) unsigned short sB[128 * 32];
  int m0 = blockIdx.x * 64, n0 = blockIdx.y * 128;
  const f32x4 vzero = {0.f, 0.f, 0.f, 0.f};
  f32x4 acc[8];
#pragma unroll
  for (int i = 0; i < 8; ++i) acc[i] = vzero;
  gemm_core<64>(p0b, NP, m0, encWt, NP, n0, NP, sA, sB, acc);

  const int tid = threadIdx.x, wave = tid >> 6, lane = tid & 63;
  const int quad = lane >> 4, lr = lane & 15, wm = wave >> 1, wn = wave & 1;
#pragma unroll
  for (int fm = 0; fm < 2; ++fm)
#pragma unroll
    for (int fn = 0; fn < 4; ++fn)
#pragma unroll
      for (int reg = 0; reg < 4; ++reg) {
        int grow = m0 + wm * 32 + fm * 16 + quad * 4 + reg;
        int gcol = n0 + wn * 64 + fn * 16 + lr;
        float val = acc[fm * 4 + fn][reg];
        if (gcol < NG)
          hbf[(size_t)grow * NG + gcol] = f32_to_bf16(val + enc1_b[gcol]);
        else
          cfp[(size_t)grow * NG + (gcol - NG)] = val + enc2_b[gcol - NG];
      }
}

// ---- one LSTM step: z = h@Ut + rank2(v_t) + bias2, fused gate update ----
__global__ __launch_bounds__(256) void k_step(
    const unsigned short* __restrict__ hin, const unsigned short* __restrict__ Ut,
    const float* __restrict__ vv, const float* __restrict__ W2r,
    const float* __restrict__ b2r, float* __restrict__ cfp,
    unsigned short* __restrict__ hout, unsigned short* __restrict__ hs, int t) {
  __shared__ __align__(16) float zt[64 * 128];   // 32 KB, unioned with staging
  __shared__ float vs0[64], vs1[64];
  unsigned short* sA = (unsigned short*)zt;            // 4 KB
  unsigned short* sB = (unsigned short*)zt + 64 * 32;  // 8 KB

  int bid = blockIdx.x;                 // 256 blocks, XCD-aware swizzle
  int xcd = bid & 7, s = bid >> 3;
  int mt = s >> 3, nsub = s & 7;
  int nt = xcd * 8 + nsub;
  int m0 = mt * 64, n0 = nt * 128;
  int tid = threadIdx.x;

  if (tid < 64) {
    int b = m0 + tid;
    vs0[tid] = vv[((size_t)b * TT + t) * 2 + 0];
    vs1[tid] = vv[((size_t)b * TT + t) * 2 + 1];
  }

  const f32x4 vzero = {0.f, 0.f, 0.f, 0.f};
  f32x4 acc[8];
#pragma unroll
  for (int i = 0; i < 8; ++i) acc[i] = vzero;
  gemm_core<64>(hin, NG, m0, Ut, NG, n0, NG, sA, sB, acc);

  const int wave = tid >> 6, lane = tid & 63;
  const int quad = lane >> 4, lr = lane & 15, wm = wave >> 1, wn = wave & 1;
  // phase 1: z (+input term +bias) -> LDS
#pragma unroll
  for (int fm = 0; fm < 2; ++fm)
#pragma unroll
    for (int fn = 0; fn < 4; ++fn)
#pragma unroll
      for (int reg = 0; reg < 4; ++reg) {
        int r  = wm * 32 + fm * 16 + quad * 4 + reg;
        int cc = wn * 64 + fn * 16 + lr;
        int gcol = n0 + cc;
        float val = acc[fm * 4 + fn][reg]
                  + vs0[r] * W2r[gcol] + vs1[r] * W2r[N4 + gcol] + b2r[gcol];
        zt[r * 128 + cc] = val;
      }
  __syncthreads();
  // phase 2: gate update for 64 rows x 32 cells
#pragma unroll
  for (int i = 0; i < 8; ++i) {
    int u = tid + i * 256;
    int r = u >> 5, j = u & 31;
    int b = m0 + r;
    int cell = (n0 >> 2) + j;
    float4 z4 = *(const float4*)(zt + r * 128 + j * 4);
    float i_ = 1.f / (1.f + __expf(-z4.x));
    float f_ = 1.f / (1.f + __expf(-z4.y));
    float g_ = fmaxf(z4.z, 0.f);
    float o_ = 1.f / (1.f + __expf(-z4.w));
    size_t ci = (size_t)b * NG + cell;
    float cn = f_ * cfp[ci] + i_ * g_;
    cfp[ci] = cn;
    unsigned short hb = f32_to_bf16(o_ * fmaxf(cn, 0.f));
    hout[ci] = hb;
    hs[((size_t)t * BB + b) * NG + cell] = hb;
  }
}

// ---- g_cells = relu(hs @ dense_W + dense_b) -> bf16 ----
__global__ __launch_bounds__(256) void k_dense(
    const unsigned short* __restrict__ hs, const unsigned short* __restrict__ dWt,
    const float* __restrict__ dense_b, unsigned short* __restrict__ gc) {
  __shared__ __align__(16) unsigned short sA[128 * 32];
  __shared__ __align__(16) unsigned short sB[128 * 32];
  int m0 = blockIdx.x * 128, n0 = blockIdx.y * 128;
  const f32x4 vzero = {0.f, 0.f, 0.f, 0.f};
  f32x4 acc[16];
#pragma unroll
  for (int i = 0; i < 16; ++i) acc[i] = vzero;
  gemm_core<128>(hs, NG, m0, dWt, NG, n0, NG, sA, sB, acc);

  const int tid = threadIdx.x, wave = tid >> 6, lane = tid & 63;
  const int quad = lane >> 4, lr = lane & 15, wm = wave >> 1, wn = wave & 1;
#pragma unroll
  for (int fm = 0; fm < 4; ++fm)
#pragma unroll
    for (int fn = 0; fn < 4; ++fn)
#pragma unroll
      for (int reg = 0; reg < 4; ++reg) {
        int grow = m0 + wm * 64 + fm * 16 + quad * 4 + reg;
        int gcol = n0 + wn * 64 + fn * 16 + lr;
        float val = fmaxf(acc[fm * 4 + fn][reg] + dense_b[gcol], 0.f);
        gc[(size_t)grow * NG + gcol] = f32_to_bf16(val);
      }
}

// ---- place_preds = g_cells @ dec_W + dec_b (fp32 out, [B][T][Np]) ----
__global__ __launch_bounds__(256) void k_dec(
    const unsigned short* __restrict__ gc, const unsigned short* __restrict__ decWt,
    const float* __restrict__ dec_b, float* __restrict__ out) {
  __shared__ __align__(16) unsigned short sA[128 * 32];
  __shared__ __align__(16) unsigned short sB[128 * 32];
  int m0 = blockIdx.x * 128, n0 = blockIdx.y * 128;
  const f32x4 vzero = {0.f, 0.f, 0.f, 0.f};
  f32x4 acc[16];
#pragma unroll
  for (int i = 0; i < 16; ++i) acc[i] = vzero;
  gemm_core<128>(gc, NG, m0, decWt, NG, n0, NG, sA, sB, acc);

  const int tid = threadIdx.x, wave = tid >> 6, lane = tid & 63;
  const int quad = lane >> 4, lr = lane & 15, wm = wave >> 1, wn = wave & 1;
#pragma unroll
  for (int fm = 0; fm < 4; ++fm)
#pragma unroll
    for (int fn = 0; fn < 4; ++fn)
#pragma unroll
      for (int reg = 0; reg < 4; ++reg) {
        int grow = m0 + wm * 64 + fm * 16 + quad * 4 + reg;   // t*256+b
        int gcol = n0 + wn * 64 + fn * 16 + lr;               // 0..511
        int tt = grow >> 8, b = grow & 255;
        out[((size_t)b * TT + tt) * NP + gcol] = acc[fm * 4 + fn][reg] + dec_b[gcol];
      }
}

// =====================================================================
extern "C" void kernel_launch(void* const* d_in, const int* in_sizes, int n_in,
                              void* d_out, int out_size, void* d_ws, size_t ws_size,
                              hipStream_t stream) {
  (void)in_sizes; (void)n_in; (void)out_size; (void)ws_size;
  const float* v       = (const float*)d_in[0];
  const float* p0      = (const float*)d_in[1];
  const float* enc1_W  = (const float*)d_in[2];
  const float* enc1_b  = (const float*)d_in[3];
  const float* enc2_W  = (const float*)d_in[4];
  const float* enc2_b  = (const float*)d_in[5];
  const float* M_W     = (const float*)d_in[6];
  const float* M_b     = (const float*)d_in[7];
  const float* lstm_W  = (const float*)d_in[8];
  const float* lstm_U  = (const float*)d_in[9];
  const float* lstm_b  = (const float*)d_in[10];
  const float* dense_W = (const float*)d_in[11];
  const float* dense_b = (const float*)d_in[12];
  const float* dec_W   = (const float*)d_in[13];
  const float* dec_b   = (const float*)d_in[14];
  float* out = (float*)d_out;

  char* ws = (char*)d_ws;
  size_t off = 0;
  auto alloc = [&](size_t bytes) {
    char* p = ws + off;
    off += (bytes + 255) & ~(size_t)255;
    return p;
  };
  unsigned short* Ut    = (unsigned short*)alloc((size_t)N4 * NG * 2);   // 32 MB
  unsigned short* dWt   = (unsigned short*)alloc((size_t)NG * NG * 2);   // 8 MB
  unsigned short* decWt = (unsigned short*)alloc((size_t)NP * NG * 2);   // 2 MB
  unsigned short* encWt = (unsigned short*)alloc((size_t)2 * NG * NP * 2);
  unsigned short* p0b   = (unsigned short*)alloc((size_t)BB * NP * 2);
  float* W2r  = (float*)alloc((size_t)2 * N4 * 4);
  float* b2r  = (float*)alloc((size_t)N4 * 4);
  float* part = (float*)alloc((size_t)16 * 3 * N4 * 4);
  float* cfp  = (float*)alloc((size_t)BB * NG * 4);
  unsigned short* hb0 = (unsigned short*)alloc((size_t)BB * NG * 2);
  unsigned short* hb1 = (unsigned short*)alloc((size_t)BB * NG * 2);
  unsigned short* hs  = (unsigned short*)alloc((size_t)MR * NG * 2);     // 100 MB
  unsigned short* gc  = (unsigned short*)alloc((size_t)MR * NG * 2);     // 100 MB

  dim3 blk(256);
  // weight conversion / transposes
  k_transpose_bf16<1><<<dim3(32, 128), blk, 0, stream>>>(lstm_U, Ut, NG, N4, 0);
  k_transpose_bf16<0><<<dim3(32, 32), blk, 0, stream>>>(dense_W, dWt, NG, NG, 0);
  k_transpose_bf16<0><<<dim3(32, 8), blk, 0, stream>>>(dec_W, decWt, NG, NP, 0);
  k_transpose_bf16<0><<<dim3(8, 32), blk, 0, stream>>>(enc1_W, encWt, NP, NG, 0);
  k_transpose_bf16<0><<<dim3(8, 32), blk, 0, stream>>>(enc2_W, encWt, NP, NG, NG);
  k_cvt<<<dim3(512), blk, 0, stream>>>(p0, p0b, BB * NP);
  // rank-2 collapse of input path
  k_prep_xw_part<<<dim3(32, 16), blk, 0, stream>>>(lstm_W, M_W, M_b, part);
  k_prep_xw_reduce<<<dim3(32), blk, 0, stream>>>(part, lstm_b, W2r, b2r);
  // initial state
  k_enc<<<dim3(4, 32), blk, 0, stream>>>(p0b, encWt, enc1_b, enc2_b, hb0, cfp);
  // recurrence
  for (int t = 0; t < TT; ++t) {
    const unsigned short* hin = (t & 1) ? hb1 : hb0;
    unsigned short* hout      = (t & 1) ? hb0 : hb1;
    k_step<<<dim3(256), blk, 0, stream>>>(hin, Ut, v, W2r, b2r, cfp, hout, hs, t);
  }
  // readout
  k_dense<<<dim3(200, 16), blk, 0, stream>>>(hs, dWt, dense_b, gc);
  k_dec<<<dim3(200, 4), blk, 0, stream>>>(gc, decWt, dec_b, out);
}